// Round 15
// baseline (60.824 us; speedup 1.0000x reference)
//
#include <hip/hip_runtime.h>
#include <math.h>

#define BB 32
#define LL 512
#define DD 1024
#define TT 256
#define NK 136393              // kept (s,e) pairs per batch
#define NK_LIN 131273          // off(502)
#define S_LIN 502
#define NEG_BIG  -3.0e38f      // finite stand-in for -inf
#define NEG_MASK -1.0e30f      // finite stand-in for masked logits
#define P_TOT (BB * NK)        // 4364576 (multiple of 4)
#define GEMV_BLOCKS (BB * LL / 4)            // 4096
#define NSEG 16                              // fill segments per batch
#define FILL_BLOCKS (BB * NSEG)              // 512
#define BCHUNKS ((NK + 255) / 256)           // 533
#define D2_BLOCKS (FILL_BLOCKS + 2 * BCHUNKS)
#define MAXW 131               // max rows (121) + 10 halo

typedef float f4v __attribute__((ext_vector_type(4)));
typedef float f2v __attribute__((ext_vector_type(2)));

// splits equalize output floats/block (~8525 each): off(s) ~ s(s+21)/2
__device__ __constant__ int d_splits[NSEG + 1] =
    {0, 121, 175, 216, 251, 282, 310, 335, 359, 381, 403, 423, 442, 460, 478, 495, 512};

__device__ __forceinline__ int off_s(int s) {
    return (s <= S_LIN) ? s * (s + 21) / 2 : NK_LIN + (s - S_LIN) * LL;
}

// ---- d1: PURE READ stream: logits = text @ W + b, wave per row -----------
__global__ __launch_bounds__(256) void gemv_kernel(
    const float* __restrict__ text, const float* __restrict__ W,
    const float* __restrict__ bias, const int* __restrict__ mask,
    float* __restrict__ slp, float* __restrict__ elp, float* __restrict__ mlp)
{
    const int wid  = threadIdx.x >> 6;
    const int lane = threadIdx.x & 63;
    const int row  = blockIdx.x * 4 + wid;        // row = b*L + l
    const f4v* t4 = (const f4v*)(text + (size_t)row * DD);
    const f4v* w4 = (const f4v*)W;
    float a0 = 0.f, a1 = 0.f, a2 = 0.f;
#pragma unroll
    for (int j = 0; j < 4; ++j) {
        const int fi = lane + j * 64;
        f4v v  = t4[fi];                          // coalesced 1KB/instr/wave
        f4v w0 = w4[fi * 3 + 0];                  // L1-hot
        f4v w1 = w4[fi * 3 + 1];
        f4v w2 = w4[fi * 3 + 2];
        a0 += v.x * w0.x;  a1 += v.x * w0.y;  a2 += v.x * w0.z;
        a0 += v.y * w0.w;  a1 += v.y * w1.x;  a2 += v.y * w1.y;
        a0 += v.z * w1.z;  a1 += v.z * w1.w;  a2 += v.z * w2.x;
        a0 += v.w * w2.y;  a1 += v.w * w2.z;  a2 += v.w * w2.w;
    }
#pragma unroll
    for (int o = 32; o; o >>= 1) {
        a0 += __shfl_down(a0, o);
        a1 += __shfl_down(a1, o);
        a2 += __shfl_down(a2, o);
    }
    if (lane == 0) {
        const int m = mask[row];
        slp[row] = (m == 1) ? a0 + bias[0] : NEG_MASK;
        elp[row] = (m == 1) ? a1 + bias[1] : NEG_MASK;
        mlp[row] = (m == 1) ? a2 + bias[2] : NEG_MASK;
    }
}

// ---- d2: PURE WRITE stream: [row-fill (scores, final values) | bounds] ---
// Fill block = (batch, balanced s-range [a,bnd)): writes its contiguous span
// [off(a), off(bnd)) exactly once -- prefix (e<s) as const f4v, tail (e>=s,
// <=11/row) computed from L2-resident logits. No memset+overwrite, no race.
__global__ __launch_bounds__(256) void fill_kernel(
    const float* __restrict__ slp, const float* __restrict__ elp,
    const float* __restrict__ mlp, const int* __restrict__ tmap,
    float* __restrict__ out)
{
    const int id = blockIdx.x;
    const int t  = threadIdx.x;

    if (id < FILL_BLOCKS) {
        const int b   = id >> 4;
        const int seg = id & 15;
        const int a   = d_splits[seg], bnd = d_splits[seg + 1];
        const int wlen = min(bnd + 10, LL) - a;   // logit/flag window rows

        __shared__ float sl[MAXW], el[MAXW], ml[MAXW];
        __shared__ unsigned char tsw[MAXW], tew[MAXW];

        for (int i = t; i < wlen; i += 256) {
            const int row = b * LL + a + i;
            sl[i] = slp[row]; el[i] = elp[row]; ml[i] = mlp[row];
            tsw[i] = 0; tew[i] = 0;
        }
        __syncthreads();
        if (t < TT) {
            int s0 = tmap[((size_t)b * TT + t) * 2 + 0];
            int e0 = tmap[((size_t)b * TT + t) * 2 + 1] - 1;
            s0 = min(max(s0, 0), LL - 1);
            e0 = min(max(e0, 0), LL - 1);
            if (s0 >= a && s0 < a + wlen) tsw[s0 - a] = 1;  // benign race
            if (e0 >= a && e0 < a + wlen) tew[e0 - a] = 1;
        }
        __syncthreads();

        const int wid = t >> 6, lane = t & 63;
        const size_t bb = (size_t)b * NK;

        for (int s = a + wid; s < bnd; s += 4) {   // wave per row, stride 4
            const int s_loc = s - a;
            const int n = min(s + 11, LL);         // row length
            const size_t rowbase = bb + off_s(s);

            auto val = [&](int e) -> float {       // final value at (s,e)
                if (e < s) return NEG_BIG;
                float v = NEG_BIG;
                if (s > 0 && tsw[s_loc] && tew[e - a]) {
                    float w = 0.f;
                    for (int l = s_loc; l <= e - a; ++l) w += ml[l];
                    v = sl[s_loc] + el[e - a] + w;
                    if (v < -1.0e29f) v = NEG_BIG; // masked -> -inf in ref
                }
                return v;
            };

            const int head = (int)((4 - (rowbase & 3)) & 3);
            const int hh = min(head, n);
            if (lane < hh) out[rowbase + lane] = val(lane);
            const int nb4 = (n - hh) >> 2;
            for (int j = lane; j < nb4; j += 64) {
                const int e0 = hh + 4 * j;
                f4v v;
                if (e0 + 3 < s) {                  // pure-prefix quad: 1 cmp
                    v = (f4v){NEG_BIG, NEG_BIG, NEG_BIG, NEG_BIG};
                } else {
                    v.x = val(e0); v.y = val(e0 + 1);
                    v.z = val(e0 + 2); v.w = val(e0 + 3);
                }
                *(f4v*)(out + rowbase + e0) = v;
            }
            const int rem = (n - hh) & 3;
            if (lane < rem) {
                const int e = hh + 4 * nb4 + lane;
                out[rowbase + e] = val(e);
            }
        }
        return;
    }

    // ---- bounds: invert pattern position once, fan out to 16 batches ----
    const int q = id - FILL_BLOCKS;
    const int g = (q >= BCHUNKS) ? 1 : 0;
    const int c = q - g * BCHUNKS;
    const int p = c * 256 + t;
    if (p >= NK) return;
    int s, e;
    if (p >= NK_LIN) {
        const int rr = p - NK_LIN;
        s = S_LIN + (rr >> 9);
        e = rr & 511;
    } else {
        float f = sqrtf(8.0f * (float)p + 441.0f);
        s = (int)((f - 21.0f) * 0.5f);
        if (s < 0) s = 0;
        if (s > 501) s = 501;
        while ((s + 1) * (s + 22) / 2 <= p) ++s;
        while (s * (s + 21) / 2 > p) --s;
        e = p - s * (s + 21) / 2;
    }
    f2v v = {(float)s, (float)e};
    f2v* bp = (f2v*)(out + (size_t)P_TOT);
#pragma unroll
    for (int j = 0; j < 16; ++j) {
        const int b = g * 16 + j;
        bp[(size_t)b * NK + p] = v;               // lane-contiguous 512B/wave
    }
}

extern "C" void kernel_launch(void* const* d_in, const int* in_sizes, int n_in,
                              void* d_out, int out_size, void* d_ws, size_t ws_size,
                              hipStream_t stream) {
    const float* text = (const float*)d_in[0];   // (B,L,D) f32
    const int*   mask = (const int*)d_in[1];     // (B,L) i32
    const int*   tmap = (const int*)d_in[2];     // (B,T,2) i32
    const float* W    = (const float*)d_in[3];   // (D,3) f32
    const float* bias = (const float*)d_in[4];   // (3,) f32
    float* out = (float*)d_out;

    float* slp = (float*)d_ws;                   // B*L each
    float* elp = slp + (size_t)BB * LL;
    float* mlp = elp + (size_t)BB * LL;

    gemv_kernel<<<GEMV_BLOCKS, 256, 0, stream>>>(text, W, bias, mask,
                                                 slp, elp, mlp);
    fill_kernel<<<D2_BLOCKS, 256, 0, stream>>>(slp, elp, mlp, tmap, out);
}

// Round 16
// 27.719 us; speedup vs baseline: 2.1943x; 2.1943x over previous
//
#include <hip/hip_runtime.h>
#include <math.h>

#define BB 32
#define LL 512
#define DD 1024
#define TT 256
#define NK 136393              // kept (s,e) pairs per batch
#define NK_LIN 131273          // off(502)
#define S_LIN 502
#define NEG_BIG  -3.0e38f      // finite stand-in for -inf
#define NEG_MASK -1.0e30f      // finite stand-in for masked logits
#define P_TOT (BB * NK)        // 4364576 (multiple of 4)
#define SC4 (P_TOT / 4)        // 1091144
#define GEMV_BLOCKS (BB * LL / 4)            // 4096
#define TAIL_CNT (BB * 11)                   // 352
#define MEMSET_CNT ((SC4 + 255) / 256)       // 4263
#define BCHUNKS ((NK + 255) / 256)           // 533
#define D2_BLOCKS (TAIL_CNT + MEMSET_CNT + 2 * BCHUNKS)

typedef float f4v __attribute__((ext_vector_type(4)));
typedef float f2v __attribute__((ext_vector_type(2)));

__device__ __forceinline__ int off_s(int s) {
    return (s <= S_LIN) ? s * (s + 21) / 2 : NK_LIN + (s - S_LIN) * LL;
}
__device__ __forceinline__ void invert(int k, int& s, int& e) {
    if (k >= NK_LIN) {
        const int r = k - NK_LIN;
        s = S_LIN + (r >> 9);
        e = r & 511;
    } else {
        float f = sqrtf(8.0f * (float)k + 441.0f);
        s = (int)((f - 21.0f) * 0.5f);
        if (s < 0) s = 0;
        if (s > 501) s = 501;
        while ((s + 1) * (s + 22) / 2 <= k) ++s;
        while (s * (s + 21) / 2 > k) --s;
        e = k - s * (s + 21) / 2;
    }
}

// ---- d1: PURE READ stream: logits = text @ W + b, wave per row (R11) -----
__global__ __launch_bounds__(256) void gemv_kernel(
    const float* __restrict__ text, const float* __restrict__ W,
    const float* __restrict__ bias, const int* __restrict__ mask,
    float* __restrict__ slp, float* __restrict__ elp, float* __restrict__ mlp)
{
    const int wid  = threadIdx.x >> 6;
    const int lane = threadIdx.x & 63;
    const int row  = blockIdx.x * 4 + wid;        // row = b*L + l
    const f4v* t4 = (const f4v*)(text + (size_t)row * DD);
    const f4v* w4 = (const f4v*)W;
    float a0 = 0.f, a1 = 0.f, a2 = 0.f;
#pragma unroll
    for (int j = 0; j < 4; ++j) {
        const int fi = lane + j * 64;
        f4v v  = t4[fi];                          // coalesced 1KB/instr/wave
        f4v w0 = w4[fi * 3 + 0];                  // L1-hot
        f4v w1 = w4[fi * 3 + 1];
        f4v w2 = w4[fi * 3 + 2];
        a0 += v.x * w0.x;  a1 += v.x * w0.y;  a2 += v.x * w0.z;
        a0 += v.y * w0.w;  a1 += v.y * w1.x;  a2 += v.y * w1.y;
        a0 += v.z * w1.z;  a1 += v.z * w1.w;  a2 += v.z * w2.x;
        a0 += v.w * w2.y;  a1 += v.w * w2.z;  a2 += v.w * w2.w;
    }
#pragma unroll
    for (int o = 32; o; o >>= 1) {
        a0 += __shfl_down(a0, o);
        a1 += __shfl_down(a1, o);
        a2 += __shfl_down(a2, o);
    }
    if (lane == 0) {
        const int m = mask[row];
        slp[row] = (m == 1) ? a0 + bias[0] : NEG_MASK;
        elp[row] = (m == 1) ? a1 + bias[1] : NEG_MASK;
        mlp[row] = (m == 1) ? a2 + bias[2] : NEG_MASK;
    }
}

// ---- d2: [tail | memset(e<s only) | bounds] -- three disjoint families ---
// tail writes ALL e>=s positions (value or NEG_BIG); memset writes ONLY e<s
// positions (exact complement, proven in R12/R13); bounds fan-out as R9/R11.
// No intra-dispatch ordering dependency anywhere.
__global__ __launch_bounds__(256) void emit_kernel(
    const float* __restrict__ slp, const float* __restrict__ elp,
    const float* __restrict__ mlp, const int* __restrict__ tmap,
    float* __restrict__ out)
{
    const int id = blockIdx.x;
    const int t  = threadIdx.x;

    if (id < TAIL_CNT) {
        // ======== tail: block (b, j=e-s); threads s = t, t+256 ========
        const int b = id / 11;
        const int j = id - b * 11;
        __shared__ float sl[LL], el[LL], ml[LL];
        __shared__ unsigned char tsl[LL], tel[LL];
        const int base = b * LL;
#pragma unroll
        for (int h = 0; h < 2; ++h) {
            const int i = t + h * 256;
            sl[i] = slp[base + i]; el[i] = elp[base + i]; ml[i] = mlp[base + i];
            tsl[i] = 0; tel[i] = 0;
        }
        __syncthreads();
        if (t < TT) {
            int s0 = tmap[((size_t)b * TT + t) * 2 + 0];
            int e0 = tmap[((size_t)b * TT + t) * 2 + 1] - 1;
            s0 = min(max(s0, 0), LL - 1);
            e0 = min(max(e0, 0), LL - 1);
            tsl[s0] = 1;                          // benign race: all write 1
            tel[e0] = 1;
        }
        __syncthreads();
#pragma unroll
        for (int h = 0; h < 2; ++h) {
            const int s = t + h * 256;
            const int e = s + j;
            if (e < LL) {
                float v = NEG_BIG;
                if (s > 0 && tsl[s] && tel[e]) {
                    float w = 0.f;
                    for (int l = s; l <= e; ++l) w += ml[l];  // <=11 LDS reads
                    v = sl[s] + el[e] + w;
                    if (v < -1.0e29f) v = NEG_BIG;  // masked -> -inf in ref
                }
                out[(size_t)b * NK + off_s(s) + e] = v;
            }
        }
        return;
    }

    if (id < TAIL_CNT + MEMSET_CNT) {
        // ======== score memset: NEG_BIG on prefix positions (e < s) ========
        const int gid = (id - TAIL_CNT) * 256 + t;
        if (gid >= SC4) return;
        const int p4 = gid * 4;
        const int b  = p4 / NK;
        const int k  = p4 - b * NK;
        int s, e;
        invert(k, s, e);
        if (e + 3 < s) {                          // whole quad in-row prefix
            f4v neg = {NEG_BIG, NEG_BIG, NEG_BIG, NEG_BIG};
            *(f4v*)(out + p4) = neg;
        } else {
            int rowlen = (s <= S_LIN) ? (s + 11) : LL;
#pragma unroll
            for (int kk = 0; kk < 4; ++kk) {
                if (e < s) out[p4 + kk] = NEG_BIG;
                ++e;
                if (e >= rowlen) {
                    e = 0; ++s;
                    if (s >= LL) s = 0;           // next batch, same pattern
                    rowlen = (s <= S_LIN) ? (s + 11) : LL;
                }
            }
        }
        return;
    }

    // ======== bounds: invert pattern position once, fan out to 16 batches ==
    const int q = id - TAIL_CNT - MEMSET_CNT;
    const int g = (q >= BCHUNKS) ? 1 : 0;
    const int c = q - g * BCHUNKS;
    const int p = c * 256 + t;
    if (p >= NK) return;
    int s, e;
    invert(p, s, e);
    f2v v = {(float)s, (float)e};
    f2v* bp = (f2v*)(out + (size_t)P_TOT);
#pragma unroll
    for (int j = 0; j < 16; ++j) {
        const int b = g * 16 + j;
        bp[(size_t)b * NK + p] = v;               // lane-contiguous 512B/wave
    }
}

extern "C" void kernel_launch(void* const* d_in, const int* in_sizes, int n_in,
                              void* d_out, int out_size, void* d_ws, size_t ws_size,
                              hipStream_t stream) {
    const float* text = (const float*)d_in[0];   // (B,L,D) f32
    const int*   mask = (const int*)d_in[1];     // (B,L) i32
    const int*   tmap = (const int*)d_in[2];     // (B,T,2) i32
    const float* W    = (const float*)d_in[3];   // (D,3) f32
    const float* bias = (const float*)d_in[4];   // (3,) f32
    float* out = (float*)d_out;

    float* slp = (float*)d_ws;                   // B*L each
    float* elp = slp + (size_t)BB * LL;
    float* mlp = elp + (size_t)BB * LL;

    gemv_kernel<<<GEMV_BLOCKS, 256, 0, stream>>>(text, W, bias, mask,
                                                 slp, elp, mlp);
    emit_kernel<<<D2_BLOCKS, 256, 0, stream>>>(slp, elp, mlp, tmap, out);
}